// Round 1
// baseline (264.732 us; speedup 1.0000x reference)
//
#include <hip/hip_runtime.h>
#include <math.h>

// Problem constants
#define BB    8
#define DIN   1024
#define TT    2048
#define KK    8192
#define DCB   8
#define NPOS  (BB*TT)        // 16384
#define ICHUNKS 8            // i-dim chunks for in_proj (128 each)
#define KCHUNKS 32           // k-dim chunks for argmin (256 each)
#define KCH     (KK/KCHUNKS) // 256

// d_out layout (float32):
//   z_q_out : [B, DIN, T]  = 16777216
//   commit  : [B]          = 8
//   cbloss  : [B]          = 8
//   indices : [B, T]       = 16384 (as float)
//   z_e     : [B, DCB, T]  = 131072
#define OFF_ZQOUT  0
#define OFF_COMMIT 16777216
#define OFF_CBLOSS 16777224
#define OFF_IDX    16777232
#define OFF_ZE     16793616

// ---------------- kernel 1: weight-norm weights + zero loss accumulators ----
__global__ __launch_bounds__(256) void k_prep_weights(
    const float* __restrict__ in_v, const float* __restrict__ in_g,
    const float* __restrict__ out_v, const float* __restrict__ out_g,
    double* __restrict__ w_in_d, float* __restrict__ w_out_f,
    double* __restrict__ lossS)
{
    __shared__ double red[256];
    int tid = threadIdx.x;
    if (tid < 16) lossS[tid] = 0.0;

    // w_in: 8 rows of 1024, fp64
    for (int r = 0; r < DCB; ++r) {
        double s = 0.0;
        for (int i = tid; i < DIN; i += 256) {
            double v = (double)in_v[r*DIN + i];
            s += v*v;
        }
        red[tid] = s; __syncthreads();
        for (int off = 128; off > 0; off >>= 1) {
            if (tid < off) red[tid] += red[tid+off];
            __syncthreads();
        }
        double nrm = sqrt(red[0]);
        __syncthreads();
        double scale = (double)in_g[r] / nrm;
        for (int i = tid; i < DIN; i += 256)
            w_in_d[r*DIN + i] = scale * (double)in_v[r*DIN + i];
    }

    // w_out: 1024 rows of 8, fp32 output (lenient threshold)
    for (int o = tid; o < DIN; o += 256) {
        float vv[DCB];
        double s = 0.0;
        for (int d = 0; d < DCB; ++d) {
            vv[d] = out_v[o*DCB + d];
            s += (double)vv[d]*(double)vv[d];
        }
        double scale = (double)out_g[o] / sqrt(s);
        for (int d = 0; d < DCB; ++d)
            w_out_f[o*DCB + d] = (float)(scale * (double)vv[d]);
    }
}

// ---------------- kernel 2: normalize codebook (fp64) ----------------------
__global__ __launch_bounds__(256) void k_prep_cb(
    const float* __restrict__ cb, double* __restrict__ cb_n,
    double* __restrict__ s_k)
{
    int k = blockIdx.x*256 + threadIdx.x;
    double v[DCB]; double s = 0.0;
    #pragma unroll
    for (int d = 0; d < DCB; ++d) {
        v[d] = (double)cb[k*DCB + d];
        s += v[d]*v[d];
    }
    double nrm = sqrt(s);
    if (nrm < 1e-12) nrm = 1e-12;
    double s2 = 0.0;
    #pragma unroll
    for (int d = 0; d < DCB; ++d) {
        double t = v[d] / nrm;
        cb_n[(size_t)k*DCB + d] = t;
        s2 += t*t;
    }
    s_k[k] = s2;
}

// ---------------- kernel 3: in-projection partial sums (fp64) --------------
// grid (NPOS/256, ICHUNKS), block 256. Each thread: one (b,t), 128 i's.
__global__ __launch_bounds__(256) void k_in_proj(
    const float* __restrict__ z, const double* __restrict__ w_in_d,
    double* __restrict__ part)
{
    __shared__ double wl[128][DCB];
    int tid = threadIdx.x;
    int chunk = blockIdx.y;
    for (int x = tid; x < 128*DCB; x += 256) {
        int ii = x >> 3, o = x & 7;
        wl[ii][o] = w_in_d[o*DIN + chunk*128 + ii];
    }
    __syncthreads();

    int pos = blockIdx.x*256 + tid;
    int b = pos >> 11, t = pos & (TT-1);
    const float* zp = z + ((size_t)b*DIN + (size_t)chunk*128)*TT + t;
    double acc[DCB] = {0,0,0,0,0,0,0,0};
    for (int ii = 0; ii < 128; ++ii) {
        double zv = (double)zp[(size_t)ii*TT];
        #pragma unroll
        for (int o = 0; o < DCB; ++o) acc[o] += wl[ii][o] * zv;
    }
    double* pp = part + ((size_t)chunk*NPOS + pos)*DCB;
    #pragma unroll
    for (int o = 0; o < DCB; ++o) pp[o] = acc[o];
}

// ---------------- kernel 4: reduce partials -> z_e, enc_n (fp64) -----------
__global__ __launch_bounds__(256) void k_reduce_ze(
    const double* __restrict__ part, const float* __restrict__ in_b,
    float* __restrict__ ze_out, double* __restrict__ enc_n,
    double* __restrict__ q_s)
{
    int pos = blockIdx.x*256 + threadIdx.x;
    int b = pos >> 11, t = pos & (TT-1);
    double v[DCB];
    double n2 = 0.0;
    #pragma unroll
    for (int o = 0; o < DCB; ++o) {
        double s = 0.0;
        for (int c = 0; c < ICHUNKS; ++c)
            s += part[((size_t)c*NPOS + pos)*DCB + o];
        s += (double)in_b[o];
        v[o] = s;
        n2 += s*s;
        ze_out[((size_t)b*DCB + o)*TT + t] = (float)s;
    }
    double nrm = sqrt(n2);
    if (nrm < 1e-12) nrm = 1e-12;
    double s2 = 0.0;
    #pragma unroll
    for (int o = 0; o < DCB; ++o) {
        double e = v[o] / nrm;
        enc_n[(size_t)pos*DCB + o] = e;
        s2 += e*e;
    }
    q_s[pos] = s2;
}

// ---------------- kernel 5: argmin partials over k-chunks (fp64) -----------
// grid (16 query-tiles of 1024, KCHUNKS), block 256, 4 queries/thread.
__global__ __launch_bounds__(256) void k_argmin_part(
    const double* __restrict__ enc_n, const double* __restrict__ q_s,
    const double* __restrict__ cb_n, const double* __restrict__ s_k,
    double* __restrict__ bestd, int* __restrict__ besti)
{
    __shared__ double cbl[KCH*DCB];
    __shared__ double skl[KCH];
    int tid = threadIdx.x;
    int qt = blockIdx.x, kc = blockIdx.y;
    int kbase = kc*KCH;

    for (int x = tid; x < KCH*DCB; x += 256)
        cbl[x] = cb_n[(size_t)kbase*DCB + x];
    for (int x = tid; x < KCH; x += 256)
        skl[x] = s_k[kbase + x];
    __syncthreads();

    double e[4][DCB]; double qs[4]; double bd[4]; int bi[4];
    #pragma unroll
    for (int j = 0; j < 4; ++j) {
        int q = qt*1024 + j*256 + tid;
        #pragma unroll
        for (int d = 0; d < DCB; ++d) e[j][d] = enc_n[(size_t)q*DCB + d];
        qs[j] = q_s[q];
        bd[j] = 1e300; bi[j] = 0;
    }

    for (int kk = 0; kk < KCH; ++kk) {
        double c0 = cbl[kk*8+0], c1 = cbl[kk*8+1], c2 = cbl[kk*8+2], c3 = cbl[kk*8+3];
        double c4 = cbl[kk*8+4], c5 = cbl[kk*8+5], c6 = cbl[kk*8+6], c7 = cbl[kk*8+7];
        double sk = skl[kk];
        int kidx = kbase + kk;
        #pragma unroll
        for (int j = 0; j < 4; ++j) {
            double dot = e[j][0]*c0 + e[j][1]*c1 + e[j][2]*c2 + e[j][3]*c3
                       + e[j][4]*c4 + e[j][5]*c5 + e[j][6]*c6 + e[j][7]*c7;
            double dist = qs[j] - 2.0*dot + sk;
            if (dist < bd[j]) { bd[j] = dist; bi[j] = kidx; }  // strict: first-min wins
        }
    }

    #pragma unroll
    for (int j = 0; j < 4; ++j) {
        int q = qt*1024 + j*256 + tid;
        bestd[(size_t)kc*NPOS + q] = bd[j];
        besti[(size_t)kc*NPOS + q] = bi[j];
    }
}

// ---------------- kernel 6: final argmin + indices + loss partials ---------
__global__ __launch_bounds__(256) void k_finalize(
    const double* __restrict__ bestd, const int* __restrict__ besti,
    const float* __restrict__ cb, const float* __restrict__ ze,
    float* __restrict__ idx_out, int* __restrict__ idx_i,
    double* __restrict__ lossS)
{
    __shared__ double red[256];
    int tid = threadIdx.x;
    int pos = blockIdx.x*256 + tid;
    int b = pos >> 11, t = pos & (TT-1);

    double bd = 1e300; int bi = 0;
    for (int c = 0; c < KCHUNKS; ++c) {   // ascending chunk order => first-min
        double d = bestd[(size_t)c*NPOS + pos];
        int i = besti[(size_t)c*NPOS + pos];
        if (d < bd) { bd = d; bi = i; }
    }
    idx_out[pos] = (float)bi;
    idx_i[pos] = bi;

    double s = 0.0;
    #pragma unroll
    for (int d = 0; d < DCB; ++d) {
        float zev = ze[((size_t)b*DCB + d)*TT + t];
        float zqv = cb[bi*DCB + d];
        double diff = (double)zev - (double)zqv;
        s += diff*diff;
    }
    red[tid] = s; __syncthreads();
    for (int off = 128; off > 0; off >>= 1) {
        if (tid < off) red[tid] += red[tid+off];
        __syncthreads();
    }
    if (tid == 0) atomicAdd(&lossS[b], red[0]);
}

// ---------------- kernel 7: write losses -----------------------------------
__global__ void k_write_losses(const double* __restrict__ lossS,
                               float* __restrict__ commit_out,
                               float* __restrict__ cbloss_out)
{
    int b = threadIdx.x;
    if (b < BB) {
        double m = lossS[b] / (double)(DCB*TT);
        commit_out[b] = (float)(m * 0.005);
        cbloss_out[b] = (float)m;
    }
}

// ---------------- kernel 8: out-projection ---------------------------------
// grid (NPOS/256, 8 o-chunks of 128), block 256.
__global__ __launch_bounds__(256) void k_out_proj(
    const float* __restrict__ cb, const float* __restrict__ ze,
    const int* __restrict__ idx_i, const float* __restrict__ w_out,
    const float* __restrict__ out_b, float* __restrict__ zq_out)
{
    __shared__ float wl[128*DCB];
    __shared__ float bl[128];
    int tid = threadIdx.x;
    int oc = blockIdx.y;
    int obase = oc*128;
    for (int x = tid; x < 128*DCB; x += 256) wl[x] = w_out[obase*DCB + x];
    for (int x = tid; x < 128; x += 256) bl[x] = out_b[obase + x];
    __syncthreads();

    int pos = blockIdx.x*256 + tid;
    int b = pos >> 11, t = pos & (TT-1);
    int ki = idx_i[pos];
    float zq[DCB];
    #pragma unroll
    for (int d = 0; d < DCB; ++d) {
        float zev = ze[((size_t)b*DCB + d)*TT + t];
        float zqv = cb[ki*DCB + d];
        zq[d] = zev + (zqv - zev);   // straight-through forward value (fp32-faithful)
    }
    float* outp = zq_out + ((size_t)b*DIN + obase)*TT + t;
    for (int oo = 0; oo < 128; ++oo) {
        float acc = 0.f;
        #pragma unroll
        for (int d = 0; d < DCB; ++d) acc += wl[oo*DCB + d]*zq[d];
        acc += bl[oo];
        outp[(size_t)oo*TT] = acc;
    }
}

// ---------------- launch ----------------------------------------------------
extern "C" void kernel_launch(void* const* d_in, const int* in_sizes, int n_in,
                              void* d_out, int out_size, void* d_ws, size_t ws_size,
                              hipStream_t stream)
{
    const float* z        = (const float*)d_in[0];
    const float* in_v     = (const float*)d_in[1];
    const float* in_g     = (const float*)d_in[2];
    const float* in_b     = (const float*)d_in[3];
    const float* out_v    = (const float*)d_in[4];
    const float* out_g    = (const float*)d_in[5];
    const float* out_b    = (const float*)d_in[6];
    const float* codebook = (const float*)d_in[7];

    float* out = (float*)d_out;
    float* zq_out_p  = out + OFF_ZQOUT;
    float* commit_p  = out + OFF_COMMIT;
    float* cbloss_p  = out + OFF_CBLOSS;
    float* idx_p     = out + OFF_IDX;
    float* ze_p      = out + OFF_ZE;

    // workspace layout (doubles first, all 8B-aligned)
    double* w_in_d = (double*)d_ws;                  // 8192
    double* cb_n   = w_in_d + 8192;                  // 65536
    double* s_k    = cb_n + 65536;                   // 8192
    double* part   = s_k + 8192;                     // ICHUNKS*NPOS*8 = 1048576
    double* enc_n  = part + (size_t)ICHUNKS*NPOS*DCB;// 131072
    double* q_s    = enc_n + (size_t)NPOS*DCB;       // 16384
    double* bestd  = q_s + NPOS;                     // KCHUNKS*NPOS = 524288
    double* lossS  = bestd + (size_t)KCHUNKS*NPOS;   // 16
    float*  w_out  = (float*)(lossS + 16);           // 8192 floats
    int*    besti  = (int*)(w_out + 8192);           // KCHUNKS*NPOS ints
    int*    idx_i  = besti + (size_t)KCHUNKS*NPOS;   // NPOS ints

    k_prep_weights<<<1, 256, 0, stream>>>(in_v, in_g, out_v, out_g, w_in_d, w_out, lossS);
    k_prep_cb<<<KK/256, 256, 0, stream>>>(codebook, cb_n, s_k);
    k_in_proj<<<dim3(NPOS/256, ICHUNKS), 256, 0, stream>>>(z, w_in_d, part);
    k_reduce_ze<<<NPOS/256, 256, 0, stream>>>(part, in_b, ze_p, enc_n, q_s);
    k_argmin_part<<<dim3(16, KCHUNKS), 256, 0, stream>>>(enc_n, q_s, cb_n, s_k, bestd, besti);
    k_finalize<<<NPOS/256, 256, 0, stream>>>(bestd, besti, codebook, ze_p, idx_p, idx_i, lossS);
    k_write_losses<<<1, 64, 0, stream>>>(lossS, commit_p, cbloss_p);
    k_out_proj<<<dim3(NPOS/256, DIN/128), 256, 0, stream>>>(codebook, ze_p, idx_i, w_out, out_b, zq_out_p);
}